// Round 7
// baseline (2972.302 us; speedup 1.0000x reference)
//
#include <hip/hip_runtime.h>
#include <math.h>

// Problem constants (fixed by reference)
#define B 128
#define R 36
#define VIS 2048
#define MM 1024
#define E 512
#define ATT 512
#define D 1024
#define V 10000
#define MAXLEN 20
#define T 19          // MAXLEN - 1
#define G4 4096       // 4*D

typedef unsigned short bf16_t;
typedef __attribute__((ext_vector_type(8))) short short8;
typedef __attribute__((ext_vector_type(4))) float f32x4;
typedef __attribute__((ext_vector_type(4))) unsigned short ushort4v;

__device__ __forceinline__ bf16_t f2bf(float f) {
    unsigned u = __float_as_uint(f);
    u += 0x7fff + ((u >> 16) & 1);   // round-to-nearest-even
    return (bf16_t)(u >> 16);
}
__device__ __forceinline__ float bf2f(bf16_t b) {
    return __uint_as_float(((unsigned)b) << 16);
}
__device__ __forceinline__ float sigmoidf_(float x) { return 1.0f / (1.0f + expf(-x)); }

// Async global->LDS, 16B per lane. LDS dest = wave-uniform base + lane*16.
__device__ __forceinline__ void stage16(const bf16_t* g, bf16_t* lds_wave_base, int lane) {
#if defined(__has_builtin) && __has_builtin(__builtin_amdgcn_global_load_lds)
    __builtin_amdgcn_global_load_lds(
        (const __attribute__((address_space(1))) void*)g,
        (__attribute__((address_space(3))) void*)lds_wave_base, 16, 0, 0);
#else
    *(short8*)(lds_wave_base + lane * 8) = *(const short8*)g;
#endif
}

// Grid-wide sync: all 256 blocks resident (1/CU, launch_bounds(256,1)).
// Device-scope atomic counter + fences (G16). Counter memset 0 each call.
__device__ __forceinline__ void gsync(unsigned* cnt, unsigned goal) {
    __syncthreads();                       // drains vmem (compiler emits vmcnt(0))
    if (threadIdx.x == 0) {
        __threadfence();                   // release
        atomicAdd(cnt, 1u);                // device-scope by default
        while (__hip_atomic_load(cnt, __ATOMIC_RELAXED, __HIP_MEMORY_SCOPE_AGENT) < goal)
            __builtin_amdgcn_s_sleep(1);
        __threadfence();                   // acquire
    }
    __syncthreads();
}

// ---------------------------------------------------------------------------
// 128x128-tile bf16 MFMA GEMM, m97 structure.
// MODE 0: C[m*ldc+n] = acc (+bias)               (fp32 out)
// MODE 2: m = t*B+b; out[(b*T+t)*V+n] = mask ? acc+bias : 0  (grid swapped)
// MODE 3: TRANSPOSED bf16 out via LDS: Cb[n*ldc+m] = bf16(acc) (grid swapped)
// ---------------------------------------------------------------------------
template<int MODE>
__global__ __launch_bounds__(256) void mfma_gemm_lds(
    const bf16_t* __restrict__ A, const bf16_t* __restrict__ W,
    const float* __restrict__ bias, const int* __restrict__ lengths,
    float* __restrict__ C, int M, int N, int K, int ldc)
{
    __shared__ __align__(16) bf16_t As[128 * 32];
    __shared__ __align__(16) bf16_t Ws[128 * 32];
    const int tid = threadIdx.x;
    const int wave = tid >> 6, lane = tid & 63;
    const int wm = wave >> 1, wn = wave & 1;
    const int quad = lane >> 4, l16 = lane & 15;
    const int m0 = ((MODE == 2 || MODE == 3) ? blockIdx.x : blockIdx.y) * 128;
    const int n0 = ((MODE == 2 || MODE == 3) ? blockIdx.y : blockIdx.x) * 128;

    f32x4 acc[4][4];
    #pragma unroll
    for (int i = 0; i < 4; ++i)
        #pragma unroll
        for (int j = 0; j < 4; ++j)
            acc[i][j] = (f32x4){0.f, 0.f, 0.f, 0.f};

    for (int kk = 0; kk < K; kk += 32) {
        #pragma unroll
        for (int i = 0; i < 2; ++i) {
            int c = tid + i * 256;          // chunk 0..511
            int row = c >> 2, seg = c & 3;
            int m = m0 + row; if (m >= M) m = M - 1;
            stage16(A + (size_t)m * K + kk + seg * 8, &As[(i * 256 + wave * 64) * 8], lane);
            int n = n0 + row; if (n >= N) n = N - 1;
            stage16(W + (size_t)n * K + kk + seg * 8, &Ws[(i * 256 + wave * 64) * 8], lane);
        }
        __syncthreads();
        short8 af[4], bfr[4];
        #pragma unroll
        for (int fm = 0; fm < 4; ++fm)
            af[fm] = *(const short8*)&As[(wm * 64 + fm * 16 + l16) * 32 + quad * 8];
        #pragma unroll
        for (int fn = 0; fn < 4; ++fn)
            bfr[fn] = *(const short8*)&Ws[(wn * 64 + fn * 16 + l16) * 32 + quad * 8];
        #pragma unroll
        for (int fm = 0; fm < 4; ++fm)
            #pragma unroll
            for (int fn = 0; fn < 4; ++fn)
                acc[fm][fn] = __builtin_amdgcn_mfma_f32_16x16x32_bf16(
                    af[fm], bfr[fn], acc[fm][fn], 0, 0, 0);
        __syncthreads();
    }

    if constexpr (MODE == 3) {
        __shared__ __align__(16) bf16_t Ct[128 * 136];
        #pragma unroll
        for (int fm = 0; fm < 4; ++fm)
            #pragma unroll
            for (int fn = 0; fn < 4; ++fn)
                #pragma unroll
                for (int r = 0; r < 4; ++r) {
                    int ml = wm * 64 + fm * 16 + quad * 4 + r;
                    int nl = wn * 64 + fn * 16 + l16;
                    Ct[nl * 136 + ml] = f2bf(acc[fm][fn][r]);
                }
        __syncthreads();
        int j = tid >> 1, half = tid & 1;
        bf16_t* Cb = (bf16_t*)C;
        #pragma unroll
        for (int s = 0; s < 8; ++s) {
            short8 v = *(const short8*)&Ct[j * 136 + half * 64 + s * 8];
            *(short8*)(Cb + (size_t)(n0 + j) * ldc + m0 + half * 64 + s * 8) = v;
        }
    } else {
        #pragma unroll
        for (int fm = 0; fm < 4; ++fm) {
            #pragma unroll
            for (int fn = 0; fn < 4; ++fn) {
                #pragma unroll
                for (int r = 0; r < 4; ++r) {
                    int m = m0 + wm * 64 + fm * 16 + quad * 4 + r;
                    int n = n0 + wn * 64 + fn * 16 + l16;
                    if (m >= M || n >= N) continue;
                    float v = acc[fm][fn][r];
                    if (MODE == 0) {
                        if (bias) v += bias[n];
                        C[(size_t)m * ldc + n] = v;
                    } else {
                        int t = m >> 7, b = m & 127;
                        v = (t < lengths[b]) ? (v + bias[n]) : 0.f;
                        C[((size_t)b * T + t) * V + n] = v;
                    }
                }
            }
        }
    }
}

// ---------------------------------------------------------------------------
// Persistent recurrence kernel: 256 blocks x 256 threads, 1 block/CU.
// Each block owns 4 d-columns (16 gathered gate-cols), Whh slice in LDS once.
// Per step: Phase A (blocks 0..127): attention -> alpha_g. gsync.
//           Phase B (all): partial = alpha.P + wordsW + bias (VALU, LDS),
//           h@Whh_slice (MFMA, A-frags direct from global L2), LSTM. gsync.
// ---------------------------------------------------------------------------
__global__ __launch_bounds__(256, 1) void recurrence_k(
    const bf16_t* __restrict__ Wh_bf,     // ATT x D
    const float*  __restrict__ att_fea,   // B x R x ATT
    const float*  __restrict__ att_bias,  // R
    const float*  __restrict__ Ww,        // ATT
    const bf16_t* __restrict__ P_t,       // G4 x (B*R)  (transposed)
    const float*  __restrict__ wordsW,    // (T*B) x G4
    const bf16_t* __restrict__ Whh_bf,    // G4 x D
    const float*  __restrict__ bih, const float* __restrict__ bhh,
    const int*    __restrict__ lengths,
    float* __restrict__ hf32,             // B x D (attention-precision h)
    bf16_t* __restrict__ hb0,             // h bf16 ping
    bf16_t* __restrict__ hb1,             // h bf16 pong
    float* __restrict__ c_st,             // B x D
    bf16_t* __restrict__ hseq,            // (T*B) x D
    float* __restrict__ alpha_g,          // B x R
    unsigned* __restrict__ barcnt)
{
    __shared__ __align__(16) bf16_t whh_s[16 * 1032];   // 33 KB (pad: 2-way banks)
    __shared__ float alpha_s[B * R];                    // 18.4 KB
    __shared__ float partial_s[16 * 132];               // 8.4 KB (pad)
    __shared__ float hs[D];                             // 4 KB   (phase A)
    __shared__ float ah_s[ATT];                         // 2 KB   (phase A)
    __shared__ float sc_s[R];

    const int tid = threadIdx.x;
    const int nb = blockIdx.x;
    const int wave = tid >> 6, lane = tid & 63;
    const int quad = lane >> 4, l16 = lane & 15;
    const int d0 = nb * 4;

    // Load gathered Whh rows (j = g*4+dd -> row g*D + d0 + dd) into LDS ONCE.
    #pragma unroll
    for (int i = 0; i < 8; ++i) {
        int c = i * 256 + tid;              // 2048 chunks of 8 elems
        int j = c >> 7, seg = c & 127;
        int row = (j >> 2) * D + d0 + (j & 3);
        *(short8*)&whh_s[j * 1032 + seg * 8] =
            *(const short8*)(Whh_bf + (size_t)row * D + seg * 8);
    }
    const int jt = tid >> 4, bg = tid & 15;
    const int rowg_t = (jt >> 2) * D + d0 + (jt & 3);
    const float bia_t = bih[rowg_t] + bhh[rowg_t];

    unsigned goal = 0;

    for (int t = 0; t < T; ++t) {
        // ---------------- Phase A: attention ----------------
        if (t > 0 && nb < B) {
            const int b = nb;
            ((float4*)hs)[tid] = ((const float4*)(hf32 + (size_t)b * D))[tid];
            __syncthreads();
            #pragma unroll 2
            for (int a = tid; a < ATT; a += 256) {
                const bf16_t* wrow = Wh_bf + (size_t)a * D;
                float s = 0.f;
                for (int k = 0; k < D; k += 8) {
                    short8 wv = *(const short8*)(wrow + k);
                    float4 ha = *(const float4*)&hs[k];
                    float4 hb = *(const float4*)&hs[k + 4];
                    s = fmaf(bf2f((bf16_t)wv[0]), ha.x, s);
                    s = fmaf(bf2f((bf16_t)wv[1]), ha.y, s);
                    s = fmaf(bf2f((bf16_t)wv[2]), ha.z, s);
                    s = fmaf(bf2f((bf16_t)wv[3]), ha.w, s);
                    s = fmaf(bf2f((bf16_t)wv[4]), hb.x, s);
                    s = fmaf(bf2f((bf16_t)wv[5]), hb.y, s);
                    s = fmaf(bf2f((bf16_t)wv[6]), hb.z, s);
                    s = fmaf(bf2f((bf16_t)wv[7]), hb.w, s);
                }
                ah_s[a] = s;
            }
            __syncthreads();
            for (int r = wave; r < R; r += 4) {
                float ab = att_bias[r];
                const float* af = att_fea + ((size_t)b * R + r) * ATT;
                float s = 0.f;
                for (int a = lane; a < ATT; a += 64) {
                    float v = af[a] + ah_s[a] + ab;
                    s = fmaf(fmaxf(v, 0.f), Ww[a], s);
                }
                #pragma unroll
                for (int off = 32; off; off >>= 1) s += __shfl_down(s, off);
                if (lane == 0) sc_s[r] = s;
            }
            __syncthreads();
            if (tid < 64) {
                float v = (tid < R) ? sc_s[tid] : -INFINITY;
                float m = v;
                #pragma unroll
                for (int off = 32; off; off >>= 1) m = fmaxf(m, __shfl_down(m, off));
                m = __shfl(m, 0);
                float e = (tid < R) ? expf(v - m) : 0.f;
                float ss = e;
                #pragma unroll
                for (int off = 32; off; off >>= 1) ss += __shfl_down(ss, off);
                ss = __shfl(ss, 0);
                if (tid < R) alpha_g[b * R + tid] = e / ss;
            }
        }
        goal += 256; gsync(barcnt, goal);

        // ---------------- Phase B ----------------
        if (t == 0) {
            for (int i = tid; i < B * R; i += 256) alpha_s[i] = 1.0f / R;
        } else {
            for (int i = tid; i < B * R; i += 256) alpha_s[i] = alpha_g[i];
        }
        __syncthreads();

        // partial[j][b] = sum_r alpha[b,r]*P_t[rowg_j][b*R+r] + wordsW + bias
        {
            const bf16_t* Pr = P_t + (size_t)rowg_t * (B * R);
            const float*  wr = wordsW + ((size_t)t * B) * G4 + rowg_t;
            #pragma unroll 2
            for (int bi = 0; bi < 8; ++bi) {
                int b = bg * 8 + bi;
                const bf16_t* p = Pr + b * R;
                const float* al = alpha_s + b * R;
                float s = 0.f;
                #pragma unroll
                for (int q4 = 0; q4 < 9; ++q4) {
                    ushort4v pv = *(const ushort4v*)(p + q4 * 4);
                    #pragma unroll
                    for (int q = 0; q < 4; ++q)
                        s = fmaf(al[q4 * 4 + q], bf2f(pv[q]), s);
                }
                partial_s[jt * 132 + b] = s + wr[(size_t)b * G4] + bia_t;
            }
        }

        // MFMA: h @ whh_slice^T  (A-frags direct from global; B from LDS)
        const bf16_t* hin = (t & 1) ? hb1 : hb0;
        bf16_t* hout = (t & 1) ? hb0 : hb1;
        f32x4 acc0 = (f32x4){0.f, 0.f, 0.f, 0.f};
        f32x4 acc1 = (f32x4){0.f, 0.f, 0.f, 0.f};
        {
            const bf16_t* a0p = hin + (size_t)(wave * 32 + l16) * D + quad * 8;
            const bf16_t* a1p = a0p + (size_t)16 * D;
            const bf16_t* bp = &whh_s[l16 * 1032 + quad * 8];
            #pragma unroll 4
            for (int kt = 0; kt < 32; ++kt) {
                short8 a0 = *(const short8*)(a0p + kt * 32);
                short8 a1 = *(const short8*)(a1p + kt * 32);
                short8 bb = *(const short8*)(bp + kt * 32);
                acc0 = __builtin_amdgcn_mfma_f32_16x16x32_bf16(a0, bb, acc0, 0, 0, 0);
                acc1 = __builtin_amdgcn_mfma_f32_16x16x32_bf16(a1, bb, acc1, 0, 0, 0);
            }
        }
        __syncthreads();    // partial_s complete before epilogue reads

        // Epilogue: gather 4 gates via shfl_xor, LSTM update
        const int g = l16 >> 2;
        const int dd = l16 & 3;
        #pragma unroll
        for (int mf = 0; mf < 2; ++mf) {
            f32x4 acc = mf ? acc1 : acc0;
            #pragma unroll
            for (int r = 0; r < 4; ++r) {
                int m = wave * 32 + mf * 16 + quad * 4 + r;
                float v = acc[r] + partial_s[l16 * 132 + m];
                float t1 = __shfl_xor(v, 4);
                float t2 = __shfl_xor(v, 8);
                float t3 = __shfl_xor(v, 12);
                float iv = (g == 0) ? v  : (g == 1) ? t1 : (g == 2) ? t2 : t3;
                float fv = (g == 0) ? t1 : (g == 1) ? v  : (g == 2) ? t3 : t2;
                float gv = (g == 0) ? t2 : (g == 1) ? t3 : (g == 2) ? v  : t1;
                float ov = (g == 0) ? t3 : (g == 1) ? t2 : (g == 2) ? t1 : v;
                if (g == 0) {
                    int d = d0 + dd;
                    size_t off = (size_t)m * D + d;
                    float c_old = c_st[off];
                    float h_old = hf32[off];
                    float ig = sigmoidf_(iv), fg = sigmoidf_(fv);
                    float gg = tanhf(gv),    og = sigmoidf_(ov);
                    float cn = fmaf(fg, c_old, ig * gg);
                    float hn = og * tanhf(cn);
                    bool msk = t < lengths[m];
                    float cv = msk ? cn : c_old;
                    float hv = msk ? hn : h_old;
                    c_st[off] = cv;
                    hf32[off] = hv;
                    bf16_t hb = f2bf(hv);
                    hout[off] = hb;
                    hseq[((size_t)t * B + m) * D + d] = hb;
                }
            }
        }
        goal += 256; gsync(barcnt, goal);
    }
}

// fp32 tile GEMM for the tiny one-shot h0/c0 init:  C = A@W^T + bias
#define TILE 64
#define KT 16
__global__ __launch_bounds__(256) void gemm_nt(
    const float* __restrict__ A, const float* __restrict__ W,
    const float* __restrict__ bias, float* __restrict__ C,
    int M, int N, int K)
{
    __shared__ float Asf[KT][TILE];
    __shared__ float Wsf[KT][TILE];
    const int tid = threadIdx.x;
    const int tx = tid & 15, ty = tid >> 4;
    const int m0 = blockIdx.y * TILE;
    const int n0 = blockIdx.x * TILE;
    const int lr = tid >> 2;
    const int lc = (tid & 3) * 4;
    float acc[4][4] = {};
    for (int kk = 0; kk < K; kk += KT) {
        {
            int m = m0 + lr;
            float4 v = make_float4(0.f, 0.f, 0.f, 0.f);
            if (m < M) v = *(const float4*)(A + (size_t)m * K + kk + lc);
            Asf[lc + 0][lr] = v.x; Asf[lc + 1][lr] = v.y;
            Asf[lc + 2][lr] = v.z; Asf[lc + 3][lr] = v.w;
        }
        {
            int n = n0 + lr;
            float4 v = make_float4(0.f, 0.f, 0.f, 0.f);
            if (n < N) v = *(const float4*)(W + (size_t)n * K + kk + lc);
            Wsf[lc + 0][lr] = v.x; Wsf[lc + 1][lr] = v.y;
            Wsf[lc + 2][lr] = v.z; Wsf[lc + 3][lr] = v.w;
        }
        __syncthreads();
        #pragma unroll
        for (int k = 0; k < KT; ++k) {
            float a[4], w[4];
            #pragma unroll
            for (int i = 0; i < 4; ++i) a[i] = Asf[k][ty * 4 + i];
            #pragma unroll
            for (int j = 0; j < 4; ++j) w[j] = Wsf[k][tx * 4 + j];
            #pragma unroll
            for (int i = 0; i < 4; ++i)
                #pragma unroll
                for (int j = 0; j < 4; ++j)
                    acc[i][j] = fmaf(a[i], w[j], acc[i][j]);
        }
        __syncthreads();
    }
    #pragma unroll
    for (int i = 0; i < 4; ++i) {
        int m = m0 + ty * 4 + i;
        if (m >= M) continue;
        #pragma unroll
        for (int j = 0; j < 4; ++j) {
            int n = n0 + tx * 4 + j;
            if (n >= N) continue;
            C[(size_t)m * N + n] = acc[i][j] + (bias ? bias[n] : 0.f);
        }
    }
}

// Strided fp32 -> bf16 cast
__global__ __launch_bounds__(256) void cast_bf16_k(
    const float* __restrict__ src, bf16_t* __restrict__ dst,
    int rows, int cols, int ld)
{
    int idx = blockIdx.x * 256 + threadIdx.x;
    int total = rows * (cols >> 2);
    if (idx >= total) return;
    int cq = cols >> 2;
    int r = idx / cq, c4 = (idx - r * cq) * 4;
    float4 v = *(const float4*)(src + (size_t)r * ld + c4);
    ushort4v o = { f2bf(v.x), f2bf(v.y), f2bf(v.z), f2bf(v.w) };
    *(ushort4v*)(dst + (size_t)r * cols + c4) = o;
}

// words_bf[(t*B+b)*E + :] = bf16(embed_W[captions[b][t]][:])
__global__ __launch_bounds__(128) void embed_k(
    const int* __restrict__ captions, const float* __restrict__ embed_W,
    bf16_t* __restrict__ words_bf)
{
    int bt = blockIdx.x;
    int b = bt / T, t = bt - b * T;
    int tok = captions[b * MAXLEN + t];
    int i = threadIdx.x * 4;
    float4 v = *(const float4*)(embed_W + (size_t)tok * E + i);
    ushort4v o = { f2bf(v.x), f2bf(v.y), f2bf(v.z), f2bf(v.w) };
    *(ushort4v*)(words_bf + ((size_t)t * B + b) * E + i) = o;
}

extern "C" void kernel_launch(void* const* d_in, const int* in_sizes, int n_in,
                              void* d_out, int out_size, void* d_ws, size_t ws_size,
                              hipStream_t stream) {
    const float* visual   = (const float*)d_in[0];
    const float* joint    = (const float*)d_in[1];
    const int*   captions = (const int*)d_in[2];
    const int*   lengths  = (const int*)d_in[3];
    const float* embed_W  = (const float*)d_in[5];
    const float* Wih      = (const float*)d_in[6];
    const float* bih      = (const float*)d_in[7];
    const float* Whh      = (const float*)d_in[8];
    const float* bhh      = (const float*)d_in[9];
    const float* W_init_h = (const float*)d_in[10];
    const float* b_init_h = (const float*)d_in[11];
    const float* W_init_c = (const float*)d_in[12];
    const float* b_init_c = (const float*)d_in[13];
    const float* Wv       = (const float*)d_in[14];
    const float* Wh       = (const float*)d_in[15];
    const float* att_bias = (const float*)d_in[16];
    const float* Ww       = (const float*)d_in[17];
    const float* Wout     = (const float*)d_in[18];
    const float* bout     = (const float*)d_in[19];
    float* out = (float*)d_out;

    // ---- workspace carve-up ----
    char* cur = (char*)d_ws;
    auto alloc = [&](size_t bytes) { char* p = cur; cur += (bytes + 15) & ~size_t(15); return p; };
    float*  att_fea  = (float*)alloc((size_t)B * R * ATT * 4);       // 9.4 MB
    float*  wordsW   = (float*)alloc((size_t)T * B * G4 * 4);        // 39.8 MB
    float*  hf       = (float*)alloc((size_t)B * D * 4);
    float*  c_st     = (float*)alloc((size_t)B * D * 4);
    float*  alpha_g  = (float*)alloc((size_t)B * R * 4);
    unsigned* barcnt = (unsigned*)alloc(64);
    bf16_t* words_bf = (bf16_t*)alloc((size_t)T * B * E * 2);
    bf16_t* h_ping0  = (bf16_t*)alloc((size_t)B * D * 2);
    bf16_t* h_ping1  = (bf16_t*)alloc((size_t)B * D * 2);
    bf16_t* hseq_bf  = (bf16_t*)alloc((size_t)T * B * D * 2);        // 5 MB
    bf16_t* P_t      = (bf16_t*)alloc((size_t)G4 * (B * R) * 2);     // 37.7 MB (transposed)
    bf16_t* visual_bf= (bf16_t*)alloc((size_t)B * R * VIS * 2);      // 18.9 MB
    bf16_t* Wv_bf    = (bf16_t*)alloc((size_t)ATT * VIS * 2);
    bf16_t* Wh_bf    = (bf16_t*)alloc((size_t)ATT * D * 2);
    bf16_t* Whh_bf   = (bf16_t*)alloc((size_t)G4 * D * 2);
    bf16_t* Wih_v_bf = (bf16_t*)alloc((size_t)G4 * VIS * 2);
    bf16_t* Wih_w_bf = (bf16_t*)alloc((size_t)G4 * E * 2);
    bf16_t* Wout_bf  = (bf16_t*)alloc((size_t)V * D * 2);

    auto cast = [&](const float* s, bf16_t* dst, int rows, int cols, int ld) {
        int total = rows * (cols >> 2);
        cast_bf16_k<<<(total + 255) / 256, 256, 0, stream>>>(s, dst, rows, cols, ld);
    };
    cast(visual, visual_bf, 1, B * R * VIS, B * R * VIS);
    cast(Wv,  Wv_bf,  ATT, VIS, VIS);
    cast(Wh,  Wh_bf,  ATT, D, D);
    cast(Whh, Whh_bf, G4, D, D);
    cast(Wih, Wih_v_bf, G4, VIS, VIS + E);
    cast(Wih + VIS, Wih_w_bf, G4, E, VIS + E);
    cast(Wout, Wout_bf, V, D, D);

    embed_k<<<B * T, 128, 0, stream>>>(captions, embed_W, words_bf);

    // h0/c0 (fp32 seed)
    gemm_nt<<<dim3(D / TILE, B / TILE), 256, 0, stream>>>(joint, W_init_h, b_init_h, hf, B, D, MM);
    gemm_nt<<<dim3(D / TILE, B / TILE), 256, 0, stream>>>(joint, W_init_c, b_init_c, c_st, B, D, MM);
    cast(hf, h_ping0, 1, B * D, B * D);

    // att_fea = visual @ Wv^T (fp32 out)
    mfma_gemm_lds<0><<<dim3(ATT / 128, (B * R) / 128), 256, 0, stream>>>(
        visual_bf, Wv_bf, nullptr, nullptr, att_fea, B * R, ATT, VIS, ATT);

    // wordsW = words @ Wih_w^T (all steps, row-major [t*B+b][G4])
    mfma_gemm_lds<0><<<dim3(G4 / 128, (T * B) / 128), 256, 0, stream>>>(
        words_bf, Wih_w_bf, nullptr, nullptr, wordsW, T * B, G4, E, G4);

    // P_t = (visual @ Wih_v^T)^T  bf16, layout [n][b*R+r]; grid m-fast for L2 reuse
    mfma_gemm_lds<3><<<dim3((B * R) / 128, G4 / 128), 256, 0, stream>>>(
        visual_bf, Wih_v_bf, nullptr, nullptr, (float*)P_t, B * R, G4, VIS, B * R);

    // ---- persistent recurrence (19 steps, 2 grid-syncs each) ----
    hipMemsetAsync(barcnt, 0, 64, stream);
    recurrence_k<<<256, 256, 0, stream>>>(
        Wh_bf, att_fea, att_bias, Ww, P_t, wordsW, Whh_bf, bih, bhh, lengths,
        hf, h_ping0, h_ping1, c_st, hseq_bf, alpha_g, barcnt);

    // ---- deferred vocab projection (grid swapped: x=m-tiles, y=n-tiles) ----
    mfma_gemm_lds<2><<<dim3((T * B) / 128, (V + 127) / 128), 256, 0, stream>>>(
        hseq_bf, Wout_bf, bout, lengths, out, T * B, V, D, V);
}